// Round 1
// baseline (589.572 us; speedup 1.0000x reference)
//
#include <hip/hip_runtime.h>
#include <hip/hip_bf16.h>
#include <math.h>

#define D_DIM 128
#define H_HEADS 8
#define HD_DIM 16
#define FF_DIM 512

// ---------------------------------------------------------------------------
// Tiled f32 GEMM: C[M,Nc] = A[M,K] @ W[Nc,K]^T + bias, optional ReLU.
// 64x64 tile, BK=16, 256 threads, 4x4 microtile per thread.
// Requires M%64==0, Nc%64==0, K%16==0 (holds: M=40000, Nc in {384,128,512}).
// ---------------------------------------------------------------------------
__global__ __launch_bounds__(256) void gemm_bias_kernel(
    const float* __restrict__ A, const float* __restrict__ W,
    const float* __restrict__ bias, float* __restrict__ C,
    int M, int Nc, int K, int relu)
{
    __shared__ float As[16][65];
    __shared__ float Ws[16][65];

    const int tid  = threadIdx.x;
    const int row0 = blockIdx.y * 64;
    const int col0 = blockIdx.x * 64;
    const int ty = tid >> 4;        // 0..15
    const int tx = tid & 15;        // 0..15
    const int lr = tid >> 2;        // 0..63 (tile row for loads)
    const int lk = (tid & 3) * 4;   // 0,4,8,12 (k offset for loads)

    float acc[4][4] = {};

    for (int k0 = 0; k0 < K; k0 += 16) {
        float4 a = *(const float4*)(A + (size_t)(row0 + lr) * K + k0 + lk);
        float4 w = *(const float4*)(W + (size_t)(col0 + lr) * K + k0 + lk);
        __syncthreads();
        As[lk + 0][lr] = a.x; As[lk + 1][lr] = a.y;
        As[lk + 2][lr] = a.z; As[lk + 3][lr] = a.w;
        Ws[lk + 0][lr] = w.x; Ws[lk + 1][lr] = w.y;
        Ws[lk + 2][lr] = w.z; Ws[lk + 3][lr] = w.w;
        __syncthreads();
#pragma unroll
        for (int k = 0; k < 16; ++k) {
            float av[4], wv[4];
#pragma unroll
            for (int i = 0; i < 4; ++i) av[i] = As[k][ty * 4 + i];
#pragma unroll
            for (int j = 0; j < 4; ++j) wv[j] = Ws[k][tx * 4 + j];
#pragma unroll
            for (int i = 0; i < 4; ++i)
#pragma unroll
                for (int j = 0; j < 4; ++j)
                    acc[i][j] += av[i] * wv[j];
        }
    }

#pragma unroll
    for (int i = 0; i < 4; ++i) {
        int r = row0 + ty * 4 + i;
#pragma unroll
        for (int j = 0; j < 4; ++j) {
            int c = col0 + tx * 4 + j;
            float v = acc[i][j] + bias[c];
            if (relu) v = fmaxf(v, 0.0f);
            C[(size_t)r * Nc + c] = v;
        }
    }
}

// ---------------------------------------------------------------------------
// CSR build: count incoming edges per target
// ---------------------------------------------------------------------------
__global__ __launch_bounds__(256) void count_kernel(
    const int* __restrict__ tgt, int* __restrict__ counts, int m)
{
    int i = blockIdx.x * blockDim.x + threadIdx.x;
    if (i < m) atomicAdd(&counts[tgt[i]], 1);
}

// Single-block exclusive scan of counts -> offsets[n+1], cursor copy.
__global__ __launch_bounds__(256) void scan_kernel(
    const int* __restrict__ counts, int* __restrict__ offsets,
    int* __restrict__ cursor, int n)
{
    __shared__ int sd[256];
    __shared__ int running_s;
    const int tid = threadIdx.x;
    if (tid == 0) running_s = 0;
    __syncthreads();

    for (int base = 0; base < n; base += 1024) {
        int idx = base + tid * 4;
        int v[4];
        int s = 0;
#pragma unroll
        for (int j = 0; j < 4; ++j) {
            v[j] = (idx + j < n) ? counts[idx + j] : 0;
            s += v[j];
        }
        sd[tid] = s;
        __syncthreads();
        for (int off = 1; off < 256; off <<= 1) {
            int t = (tid >= off) ? sd[tid - off] : 0;
            __syncthreads();
            sd[tid] += t;
            __syncthreads();
        }
        int excl = running_s + sd[tid] - s;
#pragma unroll
        for (int j = 0; j < 4; ++j) {
            if (idx + j < n) { offsets[idx + j] = excl; cursor[idx + j] = excl; }
            excl += v[j];
        }
        __syncthreads();
        if (tid == 0) running_s += sd[255];
        __syncthreads();
    }
    if (tid == 0) offsets[n] = running_s;
}

__global__ __launch_bounds__(256) void scatter_kernel(
    const int* __restrict__ src, const int* __restrict__ tgt,
    int* __restrict__ cursor, int* __restrict__ csr_src, int m)
{
    int i = blockIdx.x * blockDim.x + threadIdx.x;
    if (i < m) {
        int pos = atomicAdd(&cursor[tgt[i]], 1);
        csr_src[pos] = src[i];
    }
}

// ---------------------------------------------------------------------------
// Per-target-node attention + online softmax + weighted aggregation.
// One wave (64 lanes) per node; lane covers dims {2l, 2l+1}; head = lane>>3.
// qkv layout: [N][384] with q=0..127, k=128..255, v=256..383.
// ---------------------------------------------------------------------------
__global__ __launch_bounds__(256) void attn_aggregate_kernel(
    const float* __restrict__ qkv, const int* __restrict__ offsets,
    const int* __restrict__ csr_src, float* __restrict__ agg, int n)
{
    int node = blockIdx.x * 4 + (threadIdx.x >> 6);
    int lane = threadIdx.x & 63;
    if (node >= n) return;

    const int d0 = lane * 2;
    const float* qrow = qkv + (size_t)node * 384;
    const float q0 = qrow[d0];
    const float q1 = qrow[d0 + 1];
    const float scale = 0.25f;  // HD^-0.5 = 1/sqrt(16)

    int beg = offsets[node];
    int end = offsets[node + 1];

    float m = -INFINITY, l = 0.0f, acc0 = 0.0f, acc1 = 0.0f;

    for (int i = beg; i < end; ++i) {
        int src = csr_src[i];
        const float* krow = qkv + (size_t)src * 384 + 128;
        const float* vrow = qkv + (size_t)src * 384 + 256;
        float part = q0 * krow[d0] + q1 * krow[d0 + 1];
        // reduce within the 8-lane head group
        part += __shfl_xor(part, 1);
        part += __shfl_xor(part, 2);
        part += __shfl_xor(part, 4);
        float s = part * scale;

        float mnew = fmaxf(m, s);
        float corr = __expf(m - mnew);   // exp(-inf)=0 on first edge
        float p    = __expf(s - mnew);
        l = l * corr + p;
        float v0 = vrow[d0], v1 = vrow[d0 + 1];
        acc0 = acc0 * corr + p * v0;
        acc1 = acc1 * corr + p * v1;
        m = mnew;
    }

    float inv = (l > 0.0f) ? 1.0f / l : 0.0f;
    agg[(size_t)node * 128 + d0]     = acc0 * inv;
    agg[(size_t)node * 128 + d0 + 1] = acc1 * inv;
}

// ---------------------------------------------------------------------------
// out = LayerNorm(x + y) * g + b  (row width 128, wave per row, 2 elems/lane)
// ---------------------------------------------------------------------------
__global__ __launch_bounds__(256) void add_ln_kernel(
    const float* __restrict__ x, const float* __restrict__ y,
    const float* __restrict__ g, const float* __restrict__ b,
    float* __restrict__ out, int n)
{
    int row = blockIdx.x * 4 + (threadIdx.x >> 6);
    int lane = threadIdx.x & 63;
    if (row >= n) return;

    const int d0 = lane * 2;
    size_t base = (size_t)row * 128 + d0;
    float v0 = x[base] + y[base];
    float v1 = x[base + 1] + y[base + 1];

    float s = v0 + v1;
#pragma unroll
    for (int off = 1; off < 64; off <<= 1) s += __shfl_xor(s, off);
    float mu = s * (1.0f / 128.0f);

    float dv0 = v0 - mu, dv1 = v1 - mu;
    float ss = dv0 * dv0 + dv1 * dv1;
#pragma unroll
    for (int off = 1; off < 64; off <<= 1) ss += __shfl_xor(ss, off);
    float rstd = rsqrtf(ss * (1.0f / 128.0f) + 1e-5f);

    out[base]     = g[d0] * dv0 * rstd + b[d0];
    out[base + 1] = g[d0 + 1] * dv1 * rstd + b[d0 + 1];
}

// ---------------------------------------------------------------------------
// kernel_launch
// ---------------------------------------------------------------------------
extern "C" void kernel_launch(void* const* d_in, const int* in_sizes, int n_in,
                              void* d_out, int out_size, void* d_ws, size_t ws_size,
                              hipStream_t stream)
{
    const float* node_states = (const float*)d_in[0];
    const int*   edges       = (const int*)d_in[1];
    const float* w_qkv = (const float*)d_in[2];
    const float* b_qkv = (const float*)d_in[3];
    const float* w_out = (const float*)d_in[4];
    const float* b_out = (const float*)d_in[5];
    const float* w1    = (const float*)d_in[6];
    const float* b1    = (const float*)d_in[7];
    const float* w2    = (const float*)d_in[8];
    const float* b2    = (const float*)d_in[9];
    const float* g1    = (const float*)d_in[10];
    const float* beta1 = (const float*)d_in[11];
    const float* g2    = (const float*)d_in[12];
    const float* beta2 = (const float*)d_in[13];

    const int N = in_sizes[0] / D_DIM;   // 40000
    const int M = in_sizes[1] / 2;       // 640000
    const int* e_src = edges;
    const int* e_tgt = edges + M;

    float* out_new = (float*)d_out;
    float* out_old = (float*)d_out + (size_t)N * D_DIM;

    // workspace carve-up (256B aligned)
    size_t off = 0;
    auto alloc = [&](size_t bytes) -> void* {
        void* p = (char*)d_ws + off;
        off += (bytes + 255) & ~(size_t)255;
        return p;
    };
    // region0: qkv (N x 384) early, then ff1 (N x 512) later (qkv dead by then)
    float* region0 = (float*)alloc((size_t)N * FF_DIM * sizeof(float));
    float* qkv     = region0;
    float* ff1     = region0;
    float* agg     = (float*)alloc((size_t)N * D_DIM * sizeof(float));
    float* xbuf    = (float*)alloc((size_t)N * D_DIM * sizeof(float));
    float* msg     = (float*)alloc((size_t)N * D_DIM * sizeof(float)); // also ff2
    int* counts    = (int*)alloc((size_t)N * sizeof(int));
    int* offsets   = (int*)alloc((size_t)(N + 1) * sizeof(int));
    int* cursor    = (int*)alloc((size_t)N * sizeof(int));
    int* csr_src   = (int*)alloc((size_t)M * sizeof(int));
    (void)ws_size;

    // old node states -> second output
    hipMemcpyAsync(out_old, node_states, (size_t)N * D_DIM * sizeof(float),
                   hipMemcpyDeviceToDevice, stream);

    // 1) QKV projection: qkv[N,384] = ns @ w_qkv^T + b_qkv
    {
        dim3 grid(384 / 64, N / 64);
        gemm_bias_kernel<<<grid, 256, 0, stream>>>(node_states, w_qkv, b_qkv,
                                                   qkv, N, 384, D_DIM, 0);
    }

    // 2) CSR build by target
    hipMemsetAsync(counts, 0, (size_t)N * sizeof(int), stream);
    count_kernel<<<(M + 255) / 256, 256, 0, stream>>>(e_tgt, counts, M);
    scan_kernel<<<1, 256, 0, stream>>>(counts, offsets, cursor, N);
    scatter_kernel<<<(M + 255) / 256, 256, 0, stream>>>(e_src, e_tgt, cursor,
                                                        csr_src, M);

    // 3) per-node attention aggregation
    attn_aggregate_kernel<<<(N + 3) / 4, 256, 0, stream>>>(qkv, offsets,
                                                           csr_src, agg, N);

    // 4) messages = agg @ w_out^T + b_out
    {
        dim3 grid(128 / 64, N / 64);
        gemm_bias_kernel<<<grid, 256, 0, stream>>>(agg, w_out, b_out, msg,
                                                   N, D_DIM, D_DIM, 0);
    }

    // 5) x = LN(ns + msg)
    add_ln_kernel<<<(N + 3) / 4, 256, 0, stream>>>(node_states, msg, g1, beta1,
                                                   xbuf, N);

    // 6) ff1 = relu(x @ w1^T + b1)   (overwrites qkv region — qkv is dead)
    {
        dim3 grid(FF_DIM / 64, N / 64);
        gemm_bias_kernel<<<grid, 256, 0, stream>>>(xbuf, w1, b1, ff1,
                                                   N, FF_DIM, D_DIM, 1);
    }

    // 7) ff2 = ff1 @ w2^T + b2  (reuse msg buffer)
    {
        dim3 grid(128 / 64, N / 64);
        gemm_bias_kernel<<<grid, 256, 0, stream>>>(ff1, w2, b2, msg,
                                                   N, D_DIM, FF_DIM, 0);
    }

    // 8) out_new = LN(x + ff2)
    add_ln_kernel<<<(N + 3) / 4, 256, 0, stream>>>(xbuf, msg, g2, beta2,
                                                   out_new, N);
}

// Round 2
// 250.059 us; speedup vs baseline: 2.3577x; 2.3577x over previous
//
#include <hip/hip_runtime.h>
#include <hip/hip_bf16.h>
#include <math.h>

#define D_DIM 128
#define FF_DIM 512

typedef __attribute__((ext_vector_type(8))) short bf16x8;
typedef __attribute__((ext_vector_type(4))) float f32x4;
typedef __attribute__((ext_vector_type(4))) unsigned short u16x4;

__device__ __forceinline__ short f2bf(float f) {
    union { float f; unsigned u; } x; x.f = f;
    unsigned r = x.u + 0x7FFF + ((x.u >> 16) & 1);
    return (short)(r >> 16);
}
__device__ __forceinline__ float bf2f(short s) {
    union { unsigned u; float f; } x;
    x.u = ((unsigned)(unsigned short)s) << 16;
    return x.f;
}

__device__ __forceinline__ void load_lds16(const short* g, short* l) {
    __builtin_amdgcn_global_load_lds(
        (const __attribute__((address_space(1))) unsigned int*)g,
        (__attribute__((address_space(3))) unsigned int*)l, 16, 0, 0);
}

// ---------------------------------------------------------------------------
// bf16 MFMA GEMM: C[MP,Nc] = A[MP,K] @ W[Nc,K]^T + bias (+relu) (f32 or bf16 C)
// 128x128 tile, BK=32, 256 threads (4 waves, 2x2), 4x4 16x16 frags per wave.
// global_load_lds staging with source-pre-swizzled chunks; read applies the
// same XOR so ds_read_b128 is 2-way (free) instead of 8-way conflicted.
// Requires MP%128==0, Nc%128==0, K%32==0.
// ---------------------------------------------------------------------------
template<int OUT_BF16, int RELU>
__global__ __launch_bounds__(256) void gemm_mfma(
    const short* __restrict__ A, const short* __restrict__ B,
    const float* __restrict__ bias, void* __restrict__ C,
    int Nc, int K)
{
    __shared__ short lA[128 * 32];
    __shared__ short lB[128 * 32];

    const int tid  = threadIdx.x;
    const int lane = tid & 63;
    const int wave = tid >> 6;
    const int wr = wave >> 1, wc = wave & 1;
    const int row0 = blockIdx.y * 128;
    const int col0 = blockIdx.x * 128;
    const int fr = lane & 15;          // frag row (A) / col (B)
    const int fq = lane >> 4;          // k-quarter
    const int sw = (fr >> 1) & 3;      // read-side chunk swizzle
    const int rdoff = (fq ^ sw) * 8;   // element offset within the 32-k row

    f32x4 acc[4][4] = {};

    for (int k0 = 0; k0 < K; k0 += 32) {
        __syncthreads();
#pragma unroll
        for (int i = 0; i < 2; ++i) {
            int c  = i * 256 + tid;            // 16B chunk id 0..511
            int r  = c >> 2;                   // tile row 0..127
            int qs = c & 3;                    // LDS chunk slot in row
            int qg = qs ^ ((r >> 1) & 3);      // pre-swizzled global chunk
            load_lds16(A + (size_t)(row0 + r) * K + k0 + qg * 8, lA + c * 8);
            load_lds16(B + (size_t)(col0 + r) * K + k0 + qg * 8, lB + c * 8);
        }
        __syncthreads();

        bf16x8 af[4], bfr[4];
#pragma unroll
        for (int m = 0; m < 4; ++m)
            af[m] = *(const bf16x8*)&lA[(wr * 64 + m * 16 + fr) * 32 + rdoff];
#pragma unroll
        for (int n2 = 0; n2 < 4; ++n2)
            bfr[n2] = *(const bf16x8*)&lB[(wc * 64 + n2 * 16 + fr) * 32 + rdoff];
#pragma unroll
        for (int m = 0; m < 4; ++m)
#pragma unroll
            for (int n2 = 0; n2 < 4; ++n2)
                acc[m][n2] = __builtin_amdgcn_mfma_f32_16x16x32_bf16(
                    af[m], bfr[n2], acc[m][n2], 0, 0, 0);
    }

    // epilogue: C/D layout col=lane&15, row=(lane>>4)*4+j  [m89]
#pragma unroll
    for (int m = 0; m < 4; ++m) {
        int r = row0 + wr * 64 + m * 16 + fq * 4;
#pragma unroll
        for (int n2 = 0; n2 < 4; ++n2) {
            int c = col0 + wc * 64 + n2 * 16 + fr;
            float bb = bias[c];
#pragma unroll
            for (int j = 0; j < 4; ++j) {
                float v = acc[m][n2][j] + bb;
                if (RELU) v = fmaxf(v, 0.0f);
                if (OUT_BF16)
                    ((short*)C)[(size_t)(r + j) * Nc + c] = f2bf(v);
                else
                    ((float*)C)[(size_t)(r + j) * Nc + c] = v;
            }
        }
    }
}

// ---------------------------------------------------------------------------
// node_states f32 -> bf16 (padded rows zeroed) + copy old states to d_out
// ---------------------------------------------------------------------------
__global__ __launch_bounds__(256) void conv_ns_kernel(
    const float* __restrict__ ns, short* __restrict__ nsbf,
    float* __restrict__ out_old, int n_elems, int mp_elems)
{
    int i4 = (blockIdx.x * 256 + threadIdx.x) * 4;
    if (i4 >= mp_elems) return;
    if (i4 < n_elems) {
        float4 v = *(const float4*)(ns + i4);
        *(float4*)(out_old + i4) = v;
        u16x4 b;
        b.x = (unsigned short)f2bf(v.x); b.y = (unsigned short)f2bf(v.y);
        b.z = (unsigned short)f2bf(v.z); b.w = (unsigned short)f2bf(v.w);
        *(u16x4*)(nsbf + i4) = b;
    } else {
        u16x4 z = {0, 0, 0, 0};
        *(u16x4*)(nsbf + i4) = z;
    }
}

// all four weight matrices f32 -> bf16 in one launch
__global__ __launch_bounds__(256) void conv_w_kernel(
    const float* w0, const float* w1, const float* w2, const float* w3,
    short* o0, short* o1, short* o2, short* o3,
    int c0, int c1, int c2, int c3)
{
    int i = blockIdx.x * 256 + threadIdx.x;
    if (i < c0) o0[i] = f2bf(w0[i]);
    if (i < c1) o1[i] = f2bf(w1[i]);
    if (i < c2) o2[i] = f2bf(w2[i]);
    if (i < c3) o3[i] = f2bf(w3[i]);
}

// ---------------------------------------------------------------------------
// CSR build: count -> hierarchical scan -> scatter
// ---------------------------------------------------------------------------
__global__ __launch_bounds__(256) void count_kernel(
    const int* __restrict__ tgt, int* __restrict__ counts, int m)
{
    int i = blockIdx.x * blockDim.x + threadIdx.x;
    if (i < m) atomicAdd(&counts[tgt[i]], 1);
}

__global__ __launch_bounds__(256) void scan1_kernel(
    const int* __restrict__ counts, int* __restrict__ offs,
    int* __restrict__ bsum, int n)
{
    __shared__ int sd[256];
    int t = threadIdx.x;
    int i = blockIdx.x * 256 + t;
    int v = (i < n) ? counts[i] : 0;
    sd[t] = v;
    __syncthreads();
    for (int o = 1; o < 256; o <<= 1) {
        int x = (t >= o) ? sd[t - o] : 0;
        __syncthreads();
        sd[t] += x;
        __syncthreads();
    }
    if (i < n) offs[i] = sd[t] - v;
    if (t == 255) bsum[blockIdx.x] = sd[255];
}

__global__ __launch_bounds__(256) void scan2_kernel(
    int* __restrict__ bsum, int nb)
{
    __shared__ int sd[256];
    int t = threadIdx.x;
    int v = (t < nb) ? bsum[t] : 0;
    sd[t] = v;
    __syncthreads();
    for (int o = 1; o < 256; o <<= 1) {
        int x = (t >= o) ? sd[t - o] : 0;
        __syncthreads();
        sd[t] += x;
        __syncthreads();
    }
    if (t < nb) bsum[t] = sd[t] - v;   // exclusive
}

__global__ __launch_bounds__(256) void scan3_kernel(
    int* __restrict__ offs, const int* __restrict__ bsum,
    int* __restrict__ cursor, int n, int m)
{
    int i = blockIdx.x * 256 + threadIdx.x;
    if (i < n) {
        int v = offs[i] + bsum[blockIdx.x];
        offs[i] = v;
        cursor[i] = v;
    }
    if (i == 0) offs[n] = m;
}

__global__ __launch_bounds__(256) void scatter_kernel(
    const int* __restrict__ src, const int* __restrict__ tgt,
    int* __restrict__ cursor, int* __restrict__ csr_src, int m)
{
    int i = blockIdx.x * blockDim.x + threadIdx.x;
    if (i < m) {
        int pos = atomicAdd(&cursor[tgt[i]], 1);
        csr_src[pos] = src[i];
    }
}

// ---------------------------------------------------------------------------
// Per-target-node online-softmax attention aggregation (bf16 qkv -> bf16 agg).
// One wave per node; lane covers dims {2l,2l+1}; 8-lane groups = heads.
// qkv layout: [MP][384] bf16, q|k|v. Pad nodes write zeros.
// ---------------------------------------------------------------------------
__global__ __launch_bounds__(256) void attn_kernel(
    const short* __restrict__ qkv, const int* __restrict__ offsets,
    const int* __restrict__ csr_src, short* __restrict__ agg, int n, int mp)
{
    int node = blockIdx.x * 4 + (threadIdx.x >> 6);
    int lane = threadIdx.x & 63;
    if (node >= mp) return;
    const int d0 = lane * 2;

    if (node >= n) {
        *(unsigned*)(agg + (size_t)node * 128 + d0) = 0u;
        return;
    }

    unsigned qw = *(const unsigned*)(qkv + (size_t)node * 384 + d0);
    float q0 = bf2f((short)(qw & 0xFFFF));
    float q1 = bf2f((short)(qw >> 16));
    const float scale = 0.25f;

    int beg = offsets[node];
    int end = offsets[node + 1];

    float m = -INFINITY, l = 0.0f, acc0 = 0.0f, acc1 = 0.0f;

    for (int i = beg; i < end; ++i) {
        int src = csr_src[i];
        const short* row = qkv + (size_t)src * 384;
        unsigned kw = *(const unsigned*)(row + 128 + d0);
        unsigned vw = *(const unsigned*)(row + 256 + d0);
        float part = q0 * bf2f((short)(kw & 0xFFFF)) + q1 * bf2f((short)(kw >> 16));
        part += __shfl_xor(part, 1);
        part += __shfl_xor(part, 2);
        part += __shfl_xor(part, 4);
        float s = part * scale;

        float mnew = fmaxf(m, s);
        float corr = __expf(m - mnew);
        float p    = __expf(s - mnew);
        l = l * corr + p;
        acc0 = acc0 * corr + p * bf2f((short)(vw & 0xFFFF));
        acc1 = acc1 * corr + p * bf2f((short)(vw >> 16));
        m = mnew;
    }

    float inv = (l > 0.0f) ? 1.0f / l : 0.0f;
    unsigned out = ((unsigned)(unsigned short)f2bf(acc1 * inv) << 16) |
                   (unsigned)(unsigned short)f2bf(acc0 * inv);
    *(unsigned*)(agg + (size_t)node * 128 + d0) = out;
}

// ---------------------------------------------------------------------------
// LN1: x = LN(ns + msg); writes x f32 (rows<n) and x bf16 (pad rows zeroed)
// ---------------------------------------------------------------------------
__global__ __launch_bounds__(256) void ln1_kernel(
    const float* __restrict__ ns, const float* __restrict__ msg,
    const float* __restrict__ g, const float* __restrict__ b,
    float* __restrict__ x32, short* __restrict__ xbf, int n, int mp)
{
    int row = blockIdx.x * 4 + (threadIdx.x >> 6);
    int lane = threadIdx.x & 63;
    if (row >= mp) return;
    const int d0 = lane * 2;
    size_t base = (size_t)row * 128 + d0;

    if (row >= n) {
        *(unsigned*)(xbf + base) = 0u;
        return;
    }

    float v0 = ns[base] + msg[base];
    float v1 = ns[base + 1] + msg[base + 1];

    float s = v0 + v1;
#pragma unroll
    for (int off = 1; off < 64; off <<= 1) s += __shfl_xor(s, off);
    float mu = s * (1.0f / 128.0f);

    float dv0 = v0 - mu, dv1 = v1 - mu;
    float ss = dv0 * dv0 + dv1 * dv1;
#pragma unroll
    for (int off = 1; off < 64; off <<= 1) ss += __shfl_xor(ss, off);
    float rstd = rsqrtf(ss * (1.0f / 128.0f) + 1e-5f);

    float o0 = g[d0] * dv0 * rstd + b[d0];
    float o1 = g[d0 + 1] * dv1 * rstd + b[d0 + 1];
    x32[base] = o0;
    x32[base + 1] = o1;
    unsigned ob = ((unsigned)(unsigned short)f2bf(o1) << 16) |
                  (unsigned)(unsigned short)f2bf(o0);
    *(unsigned*)(xbf + base) = ob;
}

// LN2: out = LN(x + ff2), f32 out, rows < n
__global__ __launch_bounds__(256) void ln2_kernel(
    const float* __restrict__ x, const float* __restrict__ y,
    const float* __restrict__ g, const float* __restrict__ b,
    float* __restrict__ out, int n)
{
    int row = blockIdx.x * 4 + (threadIdx.x >> 6);
    int lane = threadIdx.x & 63;
    if (row >= n) return;
    const int d0 = lane * 2;
    size_t base = (size_t)row * 128 + d0;
    float v0 = x[base] + y[base];
    float v1 = x[base + 1] + y[base + 1];

    float s = v0 + v1;
#pragma unroll
    for (int off = 1; off < 64; off <<= 1) s += __shfl_xor(s, off);
    float mu = s * (1.0f / 128.0f);

    float dv0 = v0 - mu, dv1 = v1 - mu;
    float ss = dv0 * dv0 + dv1 * dv1;
#pragma unroll
    for (int off = 1; off < 64; off <<= 1) ss += __shfl_xor(ss, off);
    float rstd = rsqrtf(ss * (1.0f / 128.0f) + 1e-5f);

    out[base]     = g[d0] * dv0 * rstd + b[d0];
    out[base + 1] = g[d0 + 1] * dv1 * rstd + b[d0 + 1];
}

// ---------------------------------------------------------------------------
extern "C" void kernel_launch(void* const* d_in, const int* in_sizes, int n_in,
                              void* d_out, int out_size, void* d_ws, size_t ws_size,
                              hipStream_t stream)
{
    const float* node_states = (const float*)d_in[0];
    const int*   edges       = (const int*)d_in[1];
    const float* w_qkv = (const float*)d_in[2];
    const float* b_qkv = (const float*)d_in[3];
    const float* w_out = (const float*)d_in[4];
    const float* b_out = (const float*)d_in[5];
    const float* w1    = (const float*)d_in[6];
    const float* b1    = (const float*)d_in[7];
    const float* w2    = (const float*)d_in[8];
    const float* b2    = (const float*)d_in[9];
    const float* g1    = (const float*)d_in[10];
    const float* beta1 = (const float*)d_in[11];
    const float* g2    = (const float*)d_in[12];
    const float* beta2 = (const float*)d_in[13];

    const int N  = in_sizes[0] / D_DIM;      // 40000
    const int M  = in_sizes[1] / 2;          // 640000
    const int MP = ((N + 127) / 128) * 128;  // 40064
    const int* e_src = edges;
    const int* e_tgt = edges + M;

    float* out_new = (float*)d_out;
    float* out_old = (float*)d_out + (size_t)N * D_DIM;

    size_t off = 0;
    auto alloc = [&](size_t bytes) -> void* {
        void* p = (char*)d_ws + off;
        off += (bytes + 255) & ~(size_t)255;
        return p;
    };
    short* ns_bf   = (short*)alloc((size_t)MP * D_DIM * 2);
    // region: qkv_bf [MP][384] early; xbuf f32 [MP][128] + xbuf_bf [MP][128] later
    char*  region  = (char*)alloc((size_t)MP * 384 * 2);
    short* qkv_bf  = (short*)region;
    float* xbuf    = (float*)region;
    short* xbuf_bf = (short*)(region + (size_t)MP * D_DIM * 4);
    short* agg_bf  = (short*)alloc((size_t)MP * D_DIM * 2);
    float* msg     = (float*)alloc((size_t)MP * D_DIM * 4);     // also ff2 out
    short* ff1_bf  = (short*)alloc((size_t)MP * FF_DIM * 2);
    short* wqkv_bf = (short*)alloc((size_t)384 * 128 * 2);
    short* wout_bf = (short*)alloc((size_t)128 * 128 * 2);
    short* w1_bf   = (short*)alloc((size_t)512 * 128 * 2);
    short* w2_bf   = (short*)alloc((size_t)128 * 512 * 2);
    int* counts    = (int*)alloc((size_t)N * 4);
    int* offsets   = (int*)alloc((size_t)(N + 1) * 4);
    int* cursor    = (int*)alloc((size_t)N * 4);
    int* bsum      = (int*)alloc((size_t)256 * 4);
    int* csr_src   = (int*)alloc((size_t)M * 4);
    (void)ws_size;

    const int nb = (N + 255) / 256;   // 157 scan blocks

    // conversions (+ old-state copy fused)
    conv_ns_kernel<<<(MP * D_DIM / 4 + 255) / 256, 256, 0, stream>>>(
        node_states, ns_bf, out_old, N * D_DIM, MP * D_DIM);
    conv_w_kernel<<<(512 * 128 + 255) / 256, 256, 0, stream>>>(
        w_qkv, w_out, w1, w2, wqkv_bf, wout_bf, w1_bf, w2_bf,
        384 * 128, 128 * 128, 512 * 128, 128 * 512);

    // CSR build
    hipMemsetAsync(counts, 0, (size_t)N * 4, stream);
    count_kernel<<<(M + 255) / 256, 256, 0, stream>>>(e_tgt, counts, M);
    scan1_kernel<<<nb, 256, 0, stream>>>(counts, offsets, bsum, N);
    scan2_kernel<<<1, 256, 0, stream>>>(bsum, nb);
    scan3_kernel<<<nb, 256, 0, stream>>>(offsets, bsum, cursor, N, M);
    scatter_kernel<<<(M + 255) / 256, 256, 0, stream>>>(e_src, e_tgt, cursor,
                                                        csr_src, M);

    // 1) qkv = ns @ w_qkv^T + b_qkv  (bf16 out)
    {
        dim3 grid(384 / 128, MP / 128);
        gemm_mfma<1, 0><<<grid, 256, 0, stream>>>(ns_bf, wqkv_bf, b_qkv,
                                                  qkv_bf, 384, 128);
    }
    // 2) attention aggregation
    attn_kernel<<<MP / 4, 256, 0, stream>>>(qkv_bf, offsets, csr_src,
                                            agg_bf, N, MP);
    // 3) msg = agg @ w_out^T + b_out  (f32 out)
    {
        dim3 grid(1, MP / 128);
        gemm_mfma<0, 0><<<grid, 256, 0, stream>>>(agg_bf, wout_bf, b_out,
                                                  msg, 128, 128);
    }
    // 4) x = LN(ns + msg)  -> xbuf f32 + xbuf_bf   (overwrites dead qkv_bf)
    ln1_kernel<<<MP / 4, 256, 0, stream>>>(node_states, msg, g1, beta1,
                                           xbuf, xbuf_bf, N, MP);
    // 5) ff1 = relu(x @ w1^T + b1)  (bf16 out)
    {
        dim3 grid(FF_DIM / 128, MP / 128);
        gemm_mfma<1, 1><<<grid, 256, 0, stream>>>(xbuf_bf, w1_bf, b1,
                                                  ff1_bf, FF_DIM, 128);
    }
    // 6) ff2 = ff1 @ w2^T + b2  (f32 out, reuse msg)
    {
        dim3 grid(1, MP / 128);
        gemm_mfma<0, 0><<<grid, 256, 0, stream>>>(ff1_bf, w2_bf, b2,
                                                  msg, 128, 512);
    }
    // 7) out = LN(x + ff2)
    ln2_kernel<<<(N + 3) / 4, 256, 0, stream>>>(xbuf, msg, g2, beta2,
                                                out_new, N);
}